// Round 7
// baseline (431.701 us; speedup 1.0000x reference)
//
#include <hip/hip_runtime.h>
#include <hip/hip_bf16.h>

typedef __attribute__((ext_vector_type(8))) _Float16 half8;
typedef __attribute__((ext_vector_type(2))) __fp16 fp16x2;
typedef __attribute__((ext_vector_type(4))) float f32x4;

#define LOG2E 1.4426950408889634f

// ------------- kernel 1: f32 -> fp16 cast, all 3 tensors in one dispatch -----
__global__ __launch_bounds__(256) void cvt_h_kernel(const float* __restrict__ q,
                                                    const float* __restrict__ k,
                                                    const float* __restrict__ v,
                                                    _Float16* __restrict__ xq,
                                                    _Float16* __restrict__ xk,
                                                    _Float16* __restrict__ xv) {
  const int z = blockIdx.y;
  const float* x = z == 0 ? q : z == 1 ? k : v;
  _Float16* y = z == 0 ? xq : z == 1 ? xk : xv;
  size_t i = (size_t)blockIdx.x * 256 + threadIdx.x;   // 8 elems/thread
  const f32x4* p = (const f32x4*)x + i * 2;
  f32x4 a = p[0], b = p[1];
  half8 o;
  o[0] = (_Float16)a[0]; o[1] = (_Float16)a[1];
  o[2] = (_Float16)a[2]; o[3] = (_Float16)a[3];
  o[4] = (_Float16)b[0]; o[5] = (_Float16)b[1];
  o[6] = (_Float16)b[2]; o[7] = (_Float16)b[3];
  ((half8*)y)[i] = o;
}

// ------------- kernel 2: W [512k][512n] f32 -> Wt [512n][512k] fp16 (x3) -----
__global__ __launch_bounds__(256) void wtrans_kernel(const float* __restrict__ Wq,
                                                     const float* __restrict__ Wk,
                                                     const float* __restrict__ Wv,
                                                     _Float16* __restrict__ wtq,
                                                     _Float16* __restrict__ wtk,
                                                     _Float16* __restrict__ wtv) {
  const int z = blockIdx.z;
  const float* W = z == 0 ? Wq : z == 1 ? Wk : Wv;
  _Float16* Wt = z == 0 ? wtq : z == 1 ? wtk : wtv;
  __shared__ float tile[32][33];
  int k0 = blockIdx.x * 32, n0 = blockIdx.y * 32;
  int c = threadIdx.x & 31, r0 = threadIdx.x >> 5;
  #pragma unroll
  for (int rr = 0; rr < 32; rr += 8)
    tile[r0 + rr][c] = W[(size_t)(k0 + r0 + rr) * 512 + n0 + c];
  __syncthreads();
  #pragma unroll
  for (int rr = 0; rr < 32; rr += 8)
    Wt[(size_t)(n0 + r0 + rr) * 512 + k0 + c] = (_Float16)tile[c][r0 + rr];
}

// ---------------- kernel 3: all 3 projection GEMMs in one dispatch -----------
// z==0: Q out [B,H,S,64], PRE-SCALED by log2(e) for the exp2 softmax path.
// z==1: K out [B,H,S,64].  z==2: out Vt [B,H,64,S] (LDS transpose epilogue)
__global__ __launch_bounds__(256) void proj_kernel(const _Float16* __restrict__ Xq,
                                                   const _Float16* __restrict__ Xk,
                                                   const _Float16* __restrict__ Xv,
                                                   const _Float16* __restrict__ Wtq,
                                                   const _Float16* __restrict__ Wtk,
                                                   const _Float16* __restrict__ Wtv,
                                                   _Float16* __restrict__ Qp,
                                                   _Float16* __restrict__ Kp,
                                                   _Float16* __restrict__ Vt) {
  const int z = blockIdx.z;
  const _Float16* X  = z == 0 ? Xq : z == 1 ? Xk : Xv;
  const _Float16* Wt = z == 0 ? Wtq : z == 1 ? Wtk : Wtv;
  _Float16* outp     = z == 0 ? Qp : z == 1 ? Kp : Vt;

  __shared__ __align__(16) char lt_all[4 * 64 * 144];
  const int wave = threadIdx.x >> 6, lane = threadIdx.x & 63;
  const int g = lane >> 4, li = lane & 15;
  const int m0 = blockIdx.x * 128 + wave * 32;
  const int h = blockIdx.y;                    // n0 = h*64

  f32x4 acc[2][4];
  #pragma unroll
  for (int i = 0; i < 2; ++i)
    #pragma unroll
    for (int j = 0; j < 4; ++j) acc[i][j] = (f32x4){0.f, 0.f, 0.f, 0.f};

  const _Float16* xa = X + (size_t)m0 * 512;
  const _Float16* wb = Wt + (size_t)(h << 6) * 512;

  for (int k0 = 0; k0 < 512; k0 += 32) {
    half8 a[2], bw[4];
    #pragma unroll
    for (int rt = 0; rt < 2; ++rt)
      a[rt] = *(const half8*)(xa + (size_t)(rt * 16 + li) * 512 + k0 + g * 8);
    #pragma unroll
    for (int ct = 0; ct < 4; ++ct)
      bw[ct] = *(const half8*)(wb + (size_t)(ct * 16 + li) * 512 + k0 + g * 8);
    #pragma unroll
    for (int rt = 0; rt < 2; ++rt)
      #pragma unroll
      for (int ct = 0; ct < 4; ++ct)
        acc[rt][ct] = __builtin_amdgcn_mfma_f32_16x16x32_f16(a[rt], bw[ct], acc[rt][ct], 0, 0, 0);
  }

  const float qs = (z == 0) ? LOG2E : 1.0f;
  const int bidx = m0 >> 11, sbase = m0 & 2047;
  if (z != 2) {
    #pragma unroll
    for (int rt = 0; rt < 2; ++rt)
      #pragma unroll
      for (int r = 0; r < 4; ++r) {
        int s = sbase + rt * 16 + g * 4 + r;
        _Float16* orow = outp + ((size_t)((bidx * 8 + h) * 2048 + s) << 6);
        #pragma unroll
        for (int ct = 0; ct < 4; ++ct)
          orow[ct * 16 + li] = (_Float16)(acc[rt][ct][r] * qs);
      }
  } else {
    // transpose 32s x 64d tile through swizzled LDS, emit Vt rows
    char* lt = lt_all + wave * (64 * 144);
    #pragma unroll
    for (int rt = 0; rt < 2; ++rt)
      #pragma unroll
      for (int ct = 0; ct < 4; ++ct)
        #pragma unroll
        for (int r = 0; r < 4; ++r) {
          int d = ct * 16 + li, sl = rt * 16 + g * 4 + r;
          *(_Float16*)(lt + d * 144 + ((sl * 2) ^ ((d & 7) << 4))) = (_Float16)acc[rt][ct][r];
        }
    __syncthreads();
    int d = lane;  // 0..63
    _Float16* vrow = outp + (size_t)((bidx * 8 + h) * 64 + d) * 2048 + sbase;
    #pragma unroll
    for (int c = 0; c < 4; ++c) {
      half8 vv = *(half8*)(lt + d * 144 + ((c * 16) ^ ((d & 7) << 4)));
      *(half8*)(vrow + c * 8) = vv;
    }
  }
}

// ---------------- kernel 4: fused flash attention, swapped-operand form ------
// grid (S/16, B*H); block 64 (1 wave, 16 q-rows). 4096 blocks -> 16 wg/CU.
// QK^T computed as mfma(K, Q): lane holds q = lane&15 (lane-local),
// kv = 16*jt + 4*(lane>>4)+r. Softmax is in-lane; PV as mfma(Vt, P) -> O^T,
// so rescale/divide are in-lane and the store is a 16B f32x4 per lane.
__global__ __launch_bounds__(64, 4) void attn_kernel(const _Float16* __restrict__ Qp,
                                                     const _Float16* __restrict__ Kp,
                                                     const _Float16* __restrict__ Vt,
                                                     const float* __restrict__ kmask,
                                                     const float* __restrict__ rel_emb,
                                                     float* __restrict__ outp) {
  __shared__ float bias_tab[256];               // rel in [-128,127], log2 units
  __shared__ __align__(16) char pb[2048];       // P [16 q][64 kv] fp16, swizzled
  const int bh = blockIdx.y, b = bh >> 3, h = bh & 7;
  const int lane = threadIdx.x;
  const int g = lane >> 4, li = lane & 15;
  const int qw = blockIdx.x * 16;

  // T5 bucket bias (exact integer thresholds), pre-scaled by log2(e).
  for (int idx = lane; idx < 256; idx += 64) {
    int rel = idx - 128;
    int ret = rel > 0 ? 16 : 0;
    int rp = rel < 0 ? -rel : rel;
    int bb;
    if (rp < 8) bb = rp;
    else {
      int t = (rp >= 12) + (rp >= 16) + (rp >= 23) + (rp >= 32) +
              (rp >= 46) + (rp >= 64) + (rp >= 91);
      bb = 8 + t;
    }
    bias_tab[idx] = rel_emb[(ret + bb) * 8 + h] * LOG2E;
  }
  const float far_neg = rel_emb[15 * 8 + h] * LOG2E;   // rel <= -91
  const float far_pos = rel_emb[31 * 8 + h] * LOG2E;   // rel >=  91
  const float MASKC = 10000.0f * LOG2E;                // (m-1)*MASKC = (1-m)*-1e4*log2e

  const _Float16* Qb = Qp + (size_t)bh * (2048 * 64);
  const _Float16* Kb = Kp + (size_t)bh * (2048 * 64);
  const _Float16* Vb = Vt + (size_t)bh * (64 * 2048);
  const float* mkb = kmask + b * 2048;

  // Q B-fragments (col = lane&15 = q, k = 8g+e), persistent
  half8 qa[2];
  #pragma unroll
  for (int kc = 0; kc < 2; ++kc)
    qa[kc] = *(const half8*)(Qb + (size_t)(qw + li) * 64 + kc * 32 + g * 8);

  f32x4 o[4];
  #pragma unroll
  for (int ct = 0; ct < 4; ++ct) o[ct] = (f32x4){0.f, 0.f, 0.f, 0.f};
  float m = -1e30f, l = 0.f;

  const int swz = (li & 7) << 4;
  __syncthreads();   // bias table ready (single wave: cheap)

  for (int j0 = 0; j0 < 2048; j0 += 64) {
    // ---- K A-fragments (row = lane&15 = kv) ----
    half8 kb[4][2];
    #pragma unroll
    for (int jt = 0; jt < 4; ++jt)
      #pragma unroll
      for (int kc = 0; kc < 2; ++kc)
        kb[jt][kc] = *(const half8*)(Kb + (size_t)(j0 + jt * 16 + li) * 64 + kc * 32 + g * 8);

    // ---- scores^T = K Q^T : lane holds q=li, kv=16jt+4g+r ----
    f32x4 sc[4];
    #pragma unroll
    for (int jt = 0; jt < 4; ++jt) {
      f32x4 zz = (f32x4){0.f, 0.f, 0.f, 0.f};
      zz = __builtin_amdgcn_mfma_f32_16x16x32_f16(kb[jt][0], qa[0], zz, 0, 0, 0);
      sc[jt] = __builtin_amdgcn_mfma_f32_16x16x32_f16(kb[jt][1], qa[1], zz, 0, 0, 0);
    }

    // ---- bias + mask (log2 units; wave-uniform far-tile fast path) ----
    #pragma unroll
    for (int jt = 0; jt < 4; ++jt) {
      int jlo = j0 + jt * 16;
      f32x4 m4 = *(const f32x4*)(mkb + jlo + 4 * g);
      if (jlo - (qw + 15) >= 91) {
        #pragma unroll
        for (int r = 0; r < 4; ++r)
          sc[jt][r] += far_pos + (m4[r] - 1.0f) * MASKC;
      } else if (jlo + 15 - qw <= -91) {
        #pragma unroll
        for (int r = 0; r < 4; ++r)
          sc[jt][r] += far_neg + (m4[r] - 1.0f) * MASKC;
      } else {
        int base = jlo + 4 * g - qw - li + 128;
        #pragma unroll
        for (int r = 0; r < 4; ++r)
          sc[jt][r] += bias_tab[base + r] + (m4[r] - 1.0f) * MASKC;
      }
    }

    // ---- online softmax, in-lane rows (q = li) ----
    float t = sc[0][0];
    #pragma unroll
    for (int jt = 0; jt < 4; ++jt)
      #pragma unroll
      for (int r = 0; r < 4; ++r) t = fmaxf(t, sc[jt][r]);
    t = fmaxf(t, __shfl_xor(t, 16));
    t = fmaxf(t, __shfl_xor(t, 32));
    float mnew = fmaxf(m, t);
    float scal = exp2f(m - mnew);
    m = mnew;
    l *= scal;
    #pragma unroll
    for (int ct = 0; ct < 4; ++ct) o[ct] *= scal;

    // ---- P = exp2(s - m), pack pairs, one b64 LDS write per jt ----
    #pragma unroll
    for (int jt = 0; jt < 4; ++jt) {
      float p0 = exp2f(sc[jt][0] - m), p1 = exp2f(sc[jt][1] - m);
      float p2 = exp2f(sc[jt][2] - m), p3 = exp2f(sc[jt][3] - m);
      l += (p0 + p1) + (p2 + p3);
      fp16x2 h01 = __builtin_amdgcn_cvt_pkrtz(p0, p1);
      fp16x2 h23 = __builtin_amdgcn_cvt_pkrtz(p2, p3);
      uint2 w;
      w.x = __builtin_bit_cast(unsigned, h01);
      w.y = __builtin_bit_cast(unsigned, h23);
      *(uint2*)(pb + li * 128 + ((32 * jt + 8 * g) ^ swz)) = w;
    }

    // ---- O^T += Vt P^T : A = Vt (rows = d), B = P (cols = q = li) ----
    half8 pa0 = *(half8*)(pb + li * 128 + ((16 * g) ^ swz));
    half8 pa1 = *(half8*)(pb + li * 128 + ((64 + 16 * g) ^ swz));
    __builtin_amdgcn_s_setprio(1);
    #pragma unroll
    for (int dct = 0; dct < 4; ++dct) {
      half8 vb0 = *(const half8*)(Vb + (size_t)(dct * 16 + li) * 2048 + j0 + g * 8);
      half8 vb1 = *(const half8*)(Vb + (size_t)(dct * 16 + li) * 2048 + j0 + 32 + g * 8);
      o[dct] = __builtin_amdgcn_mfma_f32_16x16x32_f16(vb0, pa0, o[dct], 0, 0, 0);
      o[dct] = __builtin_amdgcn_mfma_f32_16x16x32_f16(vb1, pa1, o[dct], 0, 0, 0);
    }
    __builtin_amdgcn_s_setprio(0);
  }

  // ---- epilogue: reduce l across the 4 kv-lane-groups, divide, store ----
  float lf = l;
  lf += __shfl_xor(lf, 16);
  lf += __shfl_xor(lf, 32);
  float inv = 1.0f / lf;
  float* orow = outp + ((size_t)b * 2048 + qw + li) * 512 + h * 64;
  #pragma unroll
  for (int dct = 0; dct < 4; ++dct) {
    f32x4 ov = o[dct];
    ov[0] *= inv; ov[1] *= inv; ov[2] *= inv; ov[3] *= inv;
    *(f32x4*)(orow + dct * 16 + 4 * g) = ov;
  }
}

extern "C" void kernel_launch(void* const* d_in, const int* in_sizes, int n_in,
                              void* d_out, int out_size, void* d_ws, size_t ws_size,
                              hipStream_t stream) {
  const float* query = (const float*)d_in[0];
  const float* key   = (const float*)d_in[1];
  const float* value = (const float*)d_in[2];
  const float* kmask = (const float*)d_in[3];
  const float* Wq    = (const float*)d_in[4];
  const float* Wk    = (const float*)d_in[5];
  const float* Wv    = (const float*)d_in[6];
  const float* rel   = (const float*)d_in[7];

  char* ws = (char*)d_ws;
  const size_t SZB = 8192ull * 512 * 2;   // one f16 tensor: 8 MiB
  const size_t WB  = 512ull * 512 * 2;
  _Float16* xq  = (_Float16*)(ws);
  _Float16* xk  = (_Float16*)(ws + SZB);
  _Float16* xv  = (_Float16*)(ws + 2 * SZB);
  _Float16* wtq = (_Float16*)(ws + 3 * SZB);
  _Float16* wtk = (_Float16*)(ws + 3 * SZB + WB);
  _Float16* wtv = (_Float16*)(ws + 3 * SZB + 2 * WB);
  _Float16* qp  = (_Float16*)(ws + 3 * SZB + 3 * WB);
  _Float16* kp  = (_Float16*)(ws + 4 * SZB + 3 * WB);
  _Float16* vt  = (_Float16*)(ws + 5 * SZB + 3 * WB);

  cvt_h_kernel<<<dim3(2048, 3), dim3(256), 0, stream>>>(query, key, value, xq, xk, xv);
  wtrans_kernel<<<dim3(16, 16, 3), dim3(256), 0, stream>>>(Wq, Wk, Wv, wtq, wtk, wtv);
  proj_kernel<<<dim3(64, 8, 3), dim3(256), 0, stream>>>(xq, xk, xv, wtq, wtk, wtv, qp, kp, vt);
  attn_kernel<<<dim3(128, 32), dim3(64), 0, stream>>>(qp, kp, vt, kmask, rel, (float*)d_out);
}

// Round 9
// 326.627 us; speedup vs baseline: 1.3217x; 1.3217x over previous
//
#include <hip/hip_runtime.h>
#include <hip/hip_bf16.h>

typedef __attribute__((ext_vector_type(8))) _Float16 half8;
typedef __attribute__((ext_vector_type(2))) __fp16 fp16x2;
typedef __attribute__((ext_vector_type(4))) float f32x4;

#define LOG2E 1.4426950408889634f

// ------------- kernel 1: f32 -> fp16 cast, all 3 tensors in one dispatch -----
__global__ __launch_bounds__(256) void cvt_h_kernel(const float* __restrict__ q,
                                                    const float* __restrict__ k,
                                                    const float* __restrict__ v,
                                                    _Float16* __restrict__ xq,
                                                    _Float16* __restrict__ xk,
                                                    _Float16* __restrict__ xv) {
  const int z = blockIdx.y;
  const float* x = z == 0 ? q : z == 1 ? k : v;
  _Float16* y = z == 0 ? xq : z == 1 ? xk : xv;
  size_t i = (size_t)blockIdx.x * 256 + threadIdx.x;   // 8 elems/thread
  const f32x4* p = (const f32x4*)x + i * 2;
  f32x4 a = p[0], b = p[1];
  half8 o;
  o[0] = (_Float16)a[0]; o[1] = (_Float16)a[1];
  o[2] = (_Float16)a[2]; o[3] = (_Float16)a[3];
  o[4] = (_Float16)b[0]; o[5] = (_Float16)b[1];
  o[6] = (_Float16)b[2]; o[7] = (_Float16)b[3];
  ((half8*)y)[i] = o;
}

// ------------- kernel 2: W [512k][512n] f32 -> Wt [512n][512k] fp16 (x3) -----
__global__ __launch_bounds__(256) void wtrans_kernel(const float* __restrict__ Wq,
                                                     const float* __restrict__ Wk,
                                                     const float* __restrict__ Wv,
                                                     _Float16* __restrict__ wtq,
                                                     _Float16* __restrict__ wtk,
                                                     _Float16* __restrict__ wtv) {
  const int z = blockIdx.z;
  const float* W = z == 0 ? Wq : z == 1 ? Wk : Wv;
  _Float16* Wt = z == 0 ? wtq : z == 1 ? wtk : wtv;
  __shared__ float tile[32][33];
  int k0 = blockIdx.x * 32, n0 = blockIdx.y * 32;
  int c = threadIdx.x & 31, r0 = threadIdx.x >> 5;
  #pragma unroll
  for (int rr = 0; rr < 32; rr += 8)
    tile[r0 + rr][c] = W[(size_t)(k0 + r0 + rr) * 512 + n0 + c];
  __syncthreads();
  #pragma unroll
  for (int rr = 0; rr < 32; rr += 8)
    Wt[(size_t)(n0 + r0 + rr) * 512 + k0 + c] = (_Float16)tile[c][r0 + rr];
}

// ---------------- kernel 3: all 3 projection GEMMs in one dispatch -----------
// z==0: Q out [B,H,S,64], PRE-SCALED by log2(e) for the exp2 softmax path.
// z==1: K out [B,H,S,64].  z==2: out Vt [B,H,64,S] (LDS transpose epilogue)
__global__ __launch_bounds__(256) void proj_kernel(const _Float16* __restrict__ Xq,
                                                   const _Float16* __restrict__ Xk,
                                                   const _Float16* __restrict__ Xv,
                                                   const _Float16* __restrict__ Wtq,
                                                   const _Float16* __restrict__ Wtk,
                                                   const _Float16* __restrict__ Wtv,
                                                   _Float16* __restrict__ Qp,
                                                   _Float16* __restrict__ Kp,
                                                   _Float16* __restrict__ Vt) {
  const int z = blockIdx.z;
  const _Float16* X  = z == 0 ? Xq : z == 1 ? Xk : Xv;
  const _Float16* Wt = z == 0 ? Wtq : z == 1 ? Wtk : Wtv;
  _Float16* outp     = z == 0 ? Qp : z == 1 ? Kp : Vt;

  __shared__ __align__(16) char lt_all[4 * 64 * 144];
  const int wave = threadIdx.x >> 6, lane = threadIdx.x & 63;
  const int g = lane >> 4, li = lane & 15;
  const int m0 = blockIdx.x * 128 + wave * 32;
  const int h = blockIdx.y;                    // n0 = h*64

  f32x4 acc[2][4];
  #pragma unroll
  for (int i = 0; i < 2; ++i)
    #pragma unroll
    for (int j = 0; j < 4; ++j) acc[i][j] = (f32x4){0.f, 0.f, 0.f, 0.f};

  const _Float16* xa = X + (size_t)m0 * 512;
  const _Float16* wb = Wt + (size_t)(h << 6) * 512;

  for (int k0 = 0; k0 < 512; k0 += 32) {
    half8 a[2], bw[4];
    #pragma unroll
    for (int rt = 0; rt < 2; ++rt)
      a[rt] = *(const half8*)(xa + (size_t)(rt * 16 + li) * 512 + k0 + g * 8);
    #pragma unroll
    for (int ct = 0; ct < 4; ++ct)
      bw[ct] = *(const half8*)(wb + (size_t)(ct * 16 + li) * 512 + k0 + g * 8);
    #pragma unroll
    for (int rt = 0; rt < 2; ++rt)
      #pragma unroll
      for (int ct = 0; ct < 4; ++ct)
        acc[rt][ct] = __builtin_amdgcn_mfma_f32_16x16x32_f16(a[rt], bw[ct], acc[rt][ct], 0, 0, 0);
  }

  const float qs = (z == 0) ? LOG2E : 1.0f;
  const int bidx = m0 >> 11, sbase = m0 & 2047;
  if (z != 2) {
    #pragma unroll
    for (int rt = 0; rt < 2; ++rt)
      #pragma unroll
      for (int r = 0; r < 4; ++r) {
        int s = sbase + rt * 16 + g * 4 + r;
        _Float16* orow = outp + ((size_t)((bidx * 8 + h) * 2048 + s) << 6);
        #pragma unroll
        for (int ct = 0; ct < 4; ++ct)
          orow[ct * 16 + li] = (_Float16)(acc[rt][ct][r] * qs);
      }
  } else {
    // transpose 32s x 64d tile through swizzled LDS, emit Vt rows
    char* lt = lt_all + wave * (64 * 144);
    #pragma unroll
    for (int rt = 0; rt < 2; ++rt)
      #pragma unroll
      for (int ct = 0; ct < 4; ++ct)
        #pragma unroll
        for (int r = 0; r < 4; ++r) {
          int d = ct * 16 + li, sl = rt * 16 + g * 4 + r;
          *(_Float16*)(lt + d * 144 + ((sl * 2) ^ ((d & 7) << 4))) = (_Float16)acc[rt][ct][r];
        }
    __syncthreads();
    int d = lane;  // 0..63
    _Float16* vrow = outp + (size_t)((bidx * 8 + h) * 64 + d) * 2048 + sbase;
    #pragma unroll
    for (int c = 0; c < 4; ++c) {
      half8 vv = *(half8*)(lt + d * 144 + ((c * 16) ^ ((d & 7) << 4)));
      *(half8*)(vrow + c * 8) = vv;
    }
  }
}

// ---------------- kernel 4: fused flash attention, swapped-operand form ------
// grid flat 2048 blocks of 64 (1 wave, 32 q-rows = 2 subtiles of 16).
// QK^T as mfma(K, Q): lane holds q = lane&15 lane-local; in-lane softmax.
// K double-buffered in registers (prefetch next tile before softmax/PV).
// XCD-chunked block swizzle clusters same-head blocks per XCD for L2 reuse.
__global__ __launch_bounds__(64, 2) void attn_kernel(const _Float16* __restrict__ Qp,
                                                     const _Float16* __restrict__ Kp,
                                                     const _Float16* __restrict__ Vt,
                                                     const float* __restrict__ kmask,
                                                     const float* __restrict__ rel_emb,
                                                     float* __restrict__ outp) {
  __shared__ float bias_tab[256];               // rel in [-128,127], log2 units
  __shared__ __align__(16) char pb[2 * 2048];   // P [2 sub][16 q][64 kv] f16 swz
  // bijective XCD-chunk swizzle (nwg=2048, 2048%8==0)
  const int fid = blockIdx.x;
  const int nid = (fid & 7) * 256 + (fid >> 3);
  const int qt = nid & 63, bh = nid >> 6;
  const int b = bh >> 3, h = bh & 7;
  const int lane = threadIdx.x;
  const int g = lane >> 4, li = lane & 15;
  const int qw = qt * 32;

  // T5 bucket bias (exact integer thresholds), pre-scaled by log2(e).
  for (int idx = lane; idx < 256; idx += 64) {
    int rel = idx - 128;
    int ret = rel > 0 ? 16 : 0;
    int rp = rel < 0 ? -rel : rel;
    int bb;
    if (rp < 8) bb = rp;
    else {
      int t = (rp >= 12) + (rp >= 16) + (rp >= 23) + (rp >= 32) +
              (rp >= 46) + (rp >= 64) + (rp >= 91);
      bb = 8 + t;
    }
    bias_tab[idx] = rel_emb[(ret + bb) * 8 + h] * LOG2E;
  }
  const float far_neg = rel_emb[15 * 8 + h] * LOG2E;   // rel <= -91
  const float far_pos = rel_emb[31 * 8 + h] * LOG2E;   // rel >=  91
  const float MASKC = 10000.0f * LOG2E;

  const _Float16* Qb = Qp + (size_t)bh * (2048 * 64);
  const _Float16* Kb = Kp + (size_t)bh * (2048 * 64);
  const _Float16* Vb = Vt + (size_t)bh * (64 * 2048);
  const float* mkb = kmask + b * 2048;

  // Q B-fragments for both subtiles (col = li = q, k = 8g+e), persistent
  half8 qa[2][2];
  #pragma unroll
  for (int s = 0; s < 2; ++s)
    #pragma unroll
    for (int kc = 0; kc < 2; ++kc)
      qa[s][kc] = *(const half8*)(Qb + (size_t)(qw + s * 16 + li) * 64 + kc * 32 + g * 8);

  f32x4 o[2][4];
  float m[2], l[2];
  #pragma unroll
  for (int s = 0; s < 2; ++s) {
    #pragma unroll
    for (int ct = 0; ct < 4; ++ct) o[s][ct] = (f32x4){0.f, 0.f, 0.f, 0.f};
    m[s] = -1e30f; l[s] = 0.f;
  }

  const int swz = (li & 7) << 4;
  half8 kA[4][2], kB[4][2];

  #pragma unroll
  for (int jt = 0; jt < 4; ++jt)
    #pragma unroll
    for (int kc = 0; kc < 2; ++kc)
      kA[jt][kc] = *(const half8*)(Kb + (size_t)(jt * 16 + li) * 64 + kc * 32 + g * 8);

  __syncthreads();   // bias table ready

#define PREFETCH(DST, JN)                                                        \
  {                                                                              \
    int jn_ = (JN) < 2048 ? (JN) : 0;                                            \
    _Pragma("unroll")                                                            \
    for (int jt = 0; jt < 4; ++jt)                                               \
      _Pragma("unroll")                                                          \
      for (int kc = 0; kc < 2; ++kc)                                             \
        DST[jt][kc] = *(const half8*)(Kb + (size_t)(jn_ + jt * 16 + li) * 64 +   \
                                      kc * 32 + g * 8);                          \
  }

#define PROCESS(KB, J0)                                                          \
  {                                                                              \
    const int jb = (J0);   /* hygienic: must NOT be named j0 (R8 bug) */         \
    f32x4 sc[2][4];                                                              \
    _Pragma("unroll")                                                            \
    for (int s = 0; s < 2; ++s)                                                  \
      _Pragma("unroll")                                                          \
      for (int jt = 0; jt < 4; ++jt) {                                           \
        f32x4 zz = (f32x4){0.f, 0.f, 0.f, 0.f};                                  \
        zz = __builtin_amdgcn_mfma_f32_16x16x32_f16(KB[jt][0], qa[s][0], zz, 0, 0, 0); \
        sc[s][jt] = __builtin_amdgcn_mfma_f32_16x16x32_f16(KB[jt][1], qa[s][1], zz, 0, 0, 0); \
      }                                                                          \
    _Pragma("unroll")                                                            \
    for (int jt = 0; jt < 4; ++jt) {                                             \
      int jlo = jb + jt * 16;                                                    \
      f32x4 m4 = *(const f32x4*)(mkb + jlo + 4 * g);                             \
      _Pragma("unroll")                                                          \
      for (int s = 0; s < 2; ++s) {                                              \
        int qlo = qw + s * 16;                                                   \
        if (jlo - (qlo + 15) >= 91) {                                            \
          _Pragma("unroll")                                                      \
          for (int r = 0; r < 4; ++r)                                            \
            sc[s][jt][r] += far_pos + (m4[r] - 1.0f) * MASKC;                    \
        } else if (jlo + 15 - qlo <= -91) {                                      \
          _Pragma("unroll")                                                      \
          for (int r = 0; r < 4; ++r)                                            \
            sc[s][jt][r] += far_neg + (m4[r] - 1.0f) * MASKC;                    \
        } else {                                                                 \
          int base = jlo + 4 * g - qlo - li + 128;                               \
          _Pragma("unroll")                                                      \
          for (int r = 0; r < 4; ++r)                                            \
            sc[s][jt][r] += bias_tab[base + r] + (m4[r] - 1.0f) * MASKC;         \
        }                                                                        \
      }                                                                          \
    }                                                                            \
    _Pragma("unroll")                                                            \
    for (int s = 0; s < 2; ++s) {                                                \
      float t = sc[s][0][0];                                                     \
      _Pragma("unroll")                                                          \
      for (int jt = 0; jt < 4; ++jt)                                             \
        _Pragma("unroll")                                                        \
        for (int r = 0; r < 4; ++r) t = fmaxf(t, sc[s][jt][r]);                  \
      t = fmaxf(t, __shfl_xor(t, 16));                                           \
      t = fmaxf(t, __shfl_xor(t, 32));                                           \
      float mnew = fmaxf(m[s], t);                                               \
      float scal = exp2f(m[s] - mnew);                                           \
      m[s] = mnew;                                                               \
      l[s] *= scal;                                                              \
      _Pragma("unroll")                                                          \
      for (int ct = 0; ct < 4; ++ct) o[s][ct] *= scal;                           \
      _Pragma("unroll")                                                          \
      for (int jt = 0; jt < 4; ++jt) {                                           \
        float p0 = exp2f(sc[s][jt][0] - m[s]), p1 = exp2f(sc[s][jt][1] - m[s]);  \
        float p2 = exp2f(sc[s][jt][2] - m[s]), p3 = exp2f(sc[s][jt][3] - m[s]);  \
        l[s] += (p0 + p1) + (p2 + p3);                                           \
        fp16x2 h01 = __builtin_amdgcn_cvt_pkrtz(p0, p1);                         \
        fp16x2 h23 = __builtin_amdgcn_cvt_pkrtz(p2, p3);                         \
        uint2 w;                                                                 \
        w.x = __builtin_bit_cast(unsigned, h01);                                 \
        w.y = __builtin_bit_cast(unsigned, h23);                                 \
        *(uint2*)(pb + s * 2048 + li * 128 + ((32 * jt + 8 * g) ^ swz)) = w;     \
      }                                                                          \
    }                                                                            \
    half8 pa[2][2];                                                              \
    _Pragma("unroll")                                                            \
    for (int s = 0; s < 2; ++s) {                                                \
      pa[s][0] = *(half8*)(pb + s * 2048 + li * 128 + ((16 * g) ^ swz));         \
      pa[s][1] = *(half8*)(pb + s * 2048 + li * 128 + ((64 + 16 * g) ^ swz));    \
    }                                                                            \
    __builtin_amdgcn_s_setprio(1);                                               \
    _Pragma("unroll")                                                            \
    for (int dct = 0; dct < 4; ++dct) {                                          \
      half8 vb0 = *(const half8*)(Vb + (size_t)(dct * 16 + li) * 2048 + jb + g * 8);      \
      half8 vb1 = *(const half8*)(Vb + (size_t)(dct * 16 + li) * 2048 + jb + 32 + g * 8); \
      _Pragma("unroll")                                                          \
      for (int s = 0; s < 2; ++s) {                                              \
        o[s][dct] = __builtin_amdgcn_mfma_f32_16x16x32_f16(vb0, pa[s][0], o[s][dct], 0, 0, 0); \
        o[s][dct] = __builtin_amdgcn_mfma_f32_16x16x32_f16(vb1, pa[s][1], o[s][dct], 0, 0, 0); \
      }                                                                          \
    }                                                                            \
    __builtin_amdgcn_s_setprio(0);                                               \
  }

  for (int j0 = 0; j0 < 2048; j0 += 128) {
    PREFETCH(kB, j0 + 64)
    PROCESS(kA, j0)
    PREFETCH(kA, j0 + 128)
    PROCESS(kB, j0 + 64)
  }
#undef PREFETCH
#undef PROCESS

  // ---- epilogue: reduce l across kv-lane-groups, divide, coalesced store ----
  #pragma unroll
  for (int s = 0; s < 2; ++s) {
    float lf = l[s];
    lf += __shfl_xor(lf, 16);
    lf += __shfl_xor(lf, 32);
    float inv = 1.0f / lf;
    float* orow = outp + ((size_t)b * 2048 + qw + s * 16 + li) * 512 + h * 64;
    #pragma unroll
    for (int dct = 0; dct < 4; ++dct) {
      f32x4 ov = o[s][dct];
      ov[0] *= inv; ov[1] *= inv; ov[2] *= inv; ov[3] *= inv;
      *(f32x4*)(orow + dct * 16 + 4 * g) = ov;
    }
  }
}

extern "C" void kernel_launch(void* const* d_in, const int* in_sizes, int n_in,
                              void* d_out, int out_size, void* d_ws, size_t ws_size,
                              hipStream_t stream) {
  const float* query = (const float*)d_in[0];
  const float* key   = (const float*)d_in[1];
  const float* value = (const float*)d_in[2];
  const float* kmask = (const float*)d_in[3];
  const float* Wq    = (const float*)d_in[4];
  const float* Wk    = (const float*)d_in[5];
  const float* Wv    = (const float*)d_in[6];
  const float* rel   = (const float*)d_in[7];

  char* ws = (char*)d_ws;
  const size_t SZB = 8192ull * 512 * 2;   // one f16 tensor: 8 MiB
  const size_t WB  = 512ull * 512 * 2;
  _Float16* xq  = (_Float16*)(ws);
  _Float16* xk  = (_Float16*)(ws + SZB);
  _Float16* xv  = (_Float16*)(ws + 2 * SZB);
  _Float16* wtq = (_Float16*)(ws + 3 * SZB);
  _Float16* wtk = (_Float16*)(ws + 3 * SZB + WB);
  _Float16* wtv = (_Float16*)(ws + 3 * SZB + 2 * WB);
  _Float16* qp  = (_Float16*)(ws + 3 * SZB + 3 * WB);
  _Float16* kp  = (_Float16*)(ws + 4 * SZB + 3 * WB);
  _Float16* vt  = (_Float16*)(ws + 5 * SZB + 3 * WB);

  cvt_h_kernel<<<dim3(2048, 3), dim3(256), 0, stream>>>(query, key, value, xq, xk, xv);
  wtrans_kernel<<<dim3(16, 16, 3), dim3(256), 0, stream>>>(Wq, Wk, Wv, wtq, wtk, wtv);
  proj_kernel<<<dim3(64, 8, 3), dim3(256), 0, stream>>>(xq, xk, xv, wtq, wtk, wtv, qp, kp, vt);
  attn_kernel<<<dim3(2048), dim3(64), 0, stream>>>(qp, kp, vt, kmask, rel, (float*)d_out);
}